// Round 6
// baseline (95.275 us; speedup 1.0000x reference)
//
#include <hip/hip_runtime.h>

typedef __attribute__((ext_vector_type(8))) short bf16x8;
typedef __attribute__((ext_vector_type(4))) float f32x4;

#define NSEG 64
#define NROW 8192
#define WROW 21504
#define NBPP 576          // block slots per phase
#define T0   64           // phase-0 row tile (MFMA)
#define T12  16           // phase-1/2 row tile
#define PA   136          // bf16 pitch of A tile (mult of 8 for b128 alignment)
#define PB   136          // bf16 pitch of W_T tile
#define P1   196
#define P2   164

__device__ __forceinline__ unsigned short f2bf(float f) {
    unsigned u = __float_as_uint(f);
    u += 0x7fffu + ((u >> 16) & 1u);     // round-to-nearest-even
    return (unsigned short)(u >> 16);
}

__global__ __launch_bounds__(256) void iil_kernel(
    const float* __restrict__ x0, const float* __restrict__ x1, const float* __restrict__ x2,
    const float* __restrict__ w, const int* __restrict__ counts,
    float* __restrict__ y0, float* __restrict__ y1, float* __restrict__ y2)
{
    __shared__ __align__(16) unsigned short smem_u[T0 * PA + 128 * PB]; // 52224 B
    __shared__ int sstart[NSEG + 1];
    __shared__ int t16s[NSEG + 1];
    __shared__ int t64s[NSEG + 1];

    const int t = threadIdx.x;

    if (t < NSEG) {
        int c = counts[t];
        int v = c;
        #pragma unroll
        for (int d = 1; d < NSEG; d <<= 1) {
            int u = __shfl_up(v, d, 64);
            if (t >= d) v += u;
        }
        sstart[t + 1] = v;
        int a = (c + 15) >> 4;
        #pragma unroll
        for (int d = 1; d < NSEG; d <<= 1) {
            int u = __shfl_up(a, d, 64);
            if (t >= d) a += u;
        }
        t16s[t + 1] = a;
        int b2 = (c + 63) >> 6;
        #pragma unroll
        for (int d = 1; d < NSEG; d <<= 1) {
            int u = __shfl_up(b2, d, 64);
            if (t >= d) b2 += u;
        }
        t64s[t + 1] = b2;
        if (t == 0) { sstart[0] = 0; t16s[0] = 0; t64s[0] = 0; }
    }
    __syncthreads();

    const int phase = blockIdx.x / NBPP;
    const int pb = blockIdx.x - phase * NBPP;
    const float4 z4 = make_float4(0.f, 0.f, 0.f, 0.f);
    float* sbuf = (float*)smem_u;

    if (phase == 0) {
        if (pb >= t64s[NSEG]) return;
        int lo = 0, hi = NSEG;
        while (hi - lo > 1) {
            int mid = (lo + hi) >> 1;
            if (t64s[mid] <= pb) lo = mid; else hi = mid;
        }
        const int g = lo;
        const int s = sstart[g] + (pb - t64s[g]) * T0;
        const int nr = min(T0, sstart[g + 1] - s);
        const float* __restrict__ wseg = w + (size_t)g * WROW;

        unsigned short* As = smem_u;              // A[64][PA] bf16, row-major (r, k)
        unsigned short* Bs = smem_u + T0 * PA;    // W_T[128][PB] bf16, (o, k)

        // ---- stage x0 -> bf16 A ----
        const float4* g0 = (const float4*)x0 + (size_t)s * 32;
        #pragma unroll
        for (int i = 0; i < 8; ++i) {             // 2048 float4
            int idx = t + i * 256;
            int r = idx >> 5, c4 = (idx & 31) * 4;
            float4 v = (r < nr) ? g0[idx] : z4;
            ushort4 bv;
            bv.x = f2bf(v.x); bv.y = f2bf(v.y); bv.z = f2bf(v.z); bv.w = f2bf(v.w);
            *(ushort4*)(As + r * PA + c4) = bv;
        }
        // ---- stage W0 -> bf16 W_T (transposed) ----
        #pragma unroll
        for (int i = 0; i < 8; ++i) {             // 2048 iterations -> 4096 float4
            int idx = t + i * 256;
            int k2 = idx >> 5;                    // k-pair [0,64)
            int o4 = (idx & 31) * 4;
            float4 va = *(const float4*)(wseg + (size_t)(2 * k2) * 128 + o4);
            float4 vb = *(const float4*)(wseg + (size_t)(2 * k2 + 1) * 128 + o4);
            *(ushort2*)(Bs + (size_t)(o4 + 0) * PB + 2 * k2) = make_ushort2(f2bf(va.x), f2bf(vb.x));
            *(ushort2*)(Bs + (size_t)(o4 + 1) * PB + 2 * k2) = make_ushort2(f2bf(va.y), f2bf(vb.y));
            *(ushort2*)(Bs + (size_t)(o4 + 2) * PB + 2 * k2) = make_ushort2(f2bf(va.z), f2bf(vb.z));
            *(ushort2*)(Bs + (size_t)(o4 + 3) * PB + 2 * k2) = make_ushort2(f2bf(va.w), f2bf(vb.w));
        }
        __syncthreads();

        // ---- MFMA: wave = (mp = w&1 -> M-tiles 2mp..2mp+1, np = w>>1 -> N-tiles 4np..4np+3) ----
        const int lane = t & 63;
        const int wv = t >> 6;
        const int l16 = lane & 15;
        const int quad = lane >> 4;
        const int mp = wv & 1;
        const int np = wv >> 1;

        f32x4 acc[2][4];
        #pragma unroll
        for (int mt = 0; mt < 2; ++mt)
            #pragma unroll
            for (int nt = 0; nt < 4; ++nt)
                acc[mt][nt] = (f32x4){0.f, 0.f, 0.f, 0.f};

        const unsigned short* Abase = As + ((2 * mp) * 16 + l16) * PA + quad * 8;
        const unsigned short* Bbase = Bs + (size_t)((4 * np) * 16 + l16) * PB + quad * 8;

        #pragma unroll
        for (int ks = 0; ks < 4; ++ks) {
            const int ko = ks * 32;
            bf16x8 a0 = *(const bf16x8*)(Abase + ko);
            bf16x8 a1 = *(const bf16x8*)(Abase + 16 * PA + ko);
            #pragma unroll
            for (int nt = 0; nt < 4; ++nt) {
                bf16x8 b = *(const bf16x8*)(Bbase + (size_t)nt * 16 * PB + ko);
                acc[0][nt] = __builtin_amdgcn_mfma_f32_16x16x32_bf16(a0, b, acc[0][nt], 0, 0, 0);
                acc[1][nt] = __builtin_amdgcn_mfma_f32_16x16x32_bf16(a1, b, acc[1][nt], 0, 0, 0);
            }
        }

        // ---- epilogue: C/D layout col=lane&15, row=quad*4+reg ----
        const float c0 = 0.011048543456039806f;  // 1/(8*sqrt(128))
        #pragma unroll
        for (int mt = 0; mt < 2; ++mt) {
            int rbase = (2 * mp + mt) * 16 + quad * 4;
            #pragma unroll
            for (int nt = 0; nt < 4; ++nt) {
                int col = (4 * np + nt) * 16 + l16;
                #pragma unroll
                for (int rg = 0; rg < 4; ++rg) {
                    int r = rbase + rg;
                    if (r < nr)
                        y0[(size_t)(s + r) * 128 + col] = acc[mt][nt][rg] * c0;
                }
            }
        }
    } else if (phase == 1) {
        if (pb >= t16s[NSEG]) return;
        int lo = 0, hi = NSEG;
        while (hi - lo > 1) {
            int mid = (lo + hi) >> 1;
            if (t16s[mid] <= pb) lo = mid; else hi = mid;
        }
        const int g = lo;
        const int s = sstart[g] + (pb - t16s[g]) * T12;
        const int nr = min(T12, sstart[g + 1] - s);
        const float* __restrict__ wseg = w + (size_t)g * WROW;

        float* sx1 = sbuf;
        const float4* g1 = (const float4*)x1 + (size_t)s * 48;
        #pragma unroll
        for (int i = 0; i < 3; ++i) {               // 768 float4
            int idx = t + i * 256;
            int r = idx / 48, c = idx - r * 48;
            float4 v = (r < nr) ? g1[idx] : z4;
            *(float4*)(sx1 + r * P1 + c * 4) = v;
        }
        __syncthreads();

        const int og = t & 15;
        const int r = t >> 4;
        const float* xrow = sx1 + r * P1;
        const float* wp = wseg + 16384 + og * 4;
        float acc[12];
        #pragma unroll
        for (int i = 0; i < 12; ++i) acc[i] = 0.f;
        #pragma unroll 2
        for (int kq = 0; kq < 16; ++kq) {
            float4 xq0 = *(const float4*)(xrow + 12 * kq + 0);
            float4 xq1 = *(const float4*)(xrow + 12 * kq + 4);
            float4 xq2 = *(const float4*)(xrow + 12 * kq + 8);
            float xf[12] = {xq0.x, xq0.y, xq0.z, xq0.w,
                            xq1.x, xq1.y, xq1.z, xq1.w,
                            xq2.x, xq2.y, xq2.z, xq2.w};
            #pragma unroll
            for (int kk = 0; kk < 4; ++kk) {
                float4 wv = *(const float4*)(wp + (size_t)(4 * kq + kk) * 64);
                #pragma unroll
                for (int oo = 0; oo < 4; ++oo) {
                    float wvo = (oo == 0) ? wv.x : (oo == 1) ? wv.y : (oo == 2) ? wv.z : wv.w;
                    acc[oo * 3 + 0] = fmaf(wvo, xf[kk * 3 + 0], acc[oo * 3 + 0]);
                    acc[oo * 3 + 1] = fmaf(wvo, xf[kk * 3 + 1], acc[oo * 3 + 1]);
                    acc[oo * 3 + 2] = fmaf(wvo, xf[kk * 3 + 2], acc[oo * 3 + 2]);
                }
            }
        }
        const float c1 = 0.015625f;      // 1/(8*8)
        if (r < nr) {
            float* yb = y1 + (size_t)(s + r) * 192 + og * 12;
            *(float4*)(yb + 0) = make_float4(acc[0] * c1, acc[1] * c1, acc[2] * c1, acc[3] * c1);
            *(float4*)(yb + 4) = make_float4(acc[4] * c1, acc[5] * c1, acc[6] * c1, acc[7] * c1);
            *(float4*)(yb + 8) = make_float4(acc[8] * c1, acc[9] * c1, acc[10] * c1, acc[11] * c1);
        }
    } else {
        if (pb >= t16s[NSEG]) return;
        int lo = 0, hi = NSEG;
        while (hi - lo > 1) {
            int mid = (lo + hi) >> 1;
            if (t16s[mid] <= pb) lo = mid; else hi = mid;
        }
        const int g = lo;
        const int s = sstart[g] + (pb - t16s[g]) * T12;
        const int nr = min(T12, sstart[g + 1] - s);
        const float* __restrict__ wseg = w + (size_t)g * WROW;

        float* sx2 = sbuf;
        const float4* g2 = (const float4*)x2 + (size_t)s * 40;
        #pragma unroll
        for (int i = 0; i < 3; ++i) {               // 640 float4
            int idx = t + i * 256;
            if (idx < 640) {
                int r = idx / 40, c = idx - r * 40;
                float4 v = (r < nr) ? g2[idx] : z4;
                *(float4*)(sx2 + r * P2 + c * 4) = v;
            }
        }
        __syncthreads();

        const int og = t & 15;
        const int r = t >> 4;
        const float* xrow = sx2 + r * P2;
        const float* wp = wseg + 20480 + og * 2;
        float acc[10];
        #pragma unroll
        for (int i = 0; i < 10; ++i) acc[i] = 0.f;
        #pragma unroll
        for (int kq = 0; kq < 8; ++kq) {
            float xf[20];
            #pragma unroll
            for (int j = 0; j < 5; ++j) {
                float4 v = *(const float4*)(xrow + 20 * kq + 4 * j);
                xf[4 * j + 0] = v.x; xf[4 * j + 1] = v.y; xf[4 * j + 2] = v.z; xf[4 * j + 3] = v.w;
            }
            #pragma unroll
            for (int kk = 0; kk < 4; ++kk) {
                float2 wv = *(const float2*)(wp + (size_t)(4 * kq + kk) * 32);
                #pragma unroll
                for (int i = 0; i < 5; ++i) {
                    acc[i]     = fmaf(wv.x, xf[5 * kk + i], acc[i]);
                    acc[5 + i] = fmaf(wv.y, xf[5 * kk + i], acc[5 + i]);
                }
            }
        }
        const float c2 = 0.022097086912079608f;  // 1/(8*sqrt(32))
        if (r < nr) {
            float* yb = y2 + (size_t)(s + r) * 160 + og * 10;
            #pragma unroll
            for (int i = 0; i < 5; ++i)
                *(float2*)(yb + 2 * i) = make_float2(acc[2 * i] * c2, acc[2 * i + 1] * c2);
        }
    }
}

extern "C" void kernel_launch(void* const* d_in, const int* in_sizes, int n_in,
                              void* d_out, int out_size, void* d_ws, size_t ws_size,
                              hipStream_t stream) {
    const float* x0 = (const float*)d_in[0];
    const float* x1 = (const float*)d_in[1];
    const float* x2 = (const float*)d_in[2];
    const float* w  = (const float*)d_in[3];
    const int* counts = (const int*)d_in[4];

    float* y0 = (float*)d_out;
    float* y1 = y0 + (size_t)NROW * 128;
    float* y2 = y1 + (size_t)NROW * 192;

    hipLaunchKernelGGL(iil_kernel, dim3(3 * NBPP), dim3(256), 0, stream,
                       x0, x1, x2, w, counts, y0, y1, y2);
}